// Round 16
// baseline (156.345 us; speedup 1.0000x reference)
//
#include <hip/hip_runtime.h>
#include <hip/hip_fp8.h>
#include <math.h>

typedef __bf16 bf16;
typedef __attribute__((ext_vector_type(8))) __bf16 bf16x8;
typedef __attribute__((ext_vector_type(4))) float f32x4;
typedef __attribute__((ext_vector_type(16))) float f32x16;
typedef __attribute__((ext_vector_type(8))) int i32x8;

#define M_TOK 4096
#define MREF 8.0f   // fixed logsumexp reference (logits bounded ~|4|)

// ---------------- helpers ----------------

__device__ __forceinline__ void gl_lds16(const void* g, void* l) {
  __builtin_amdgcn_global_load_lds(
      (const __attribute__((address_space(1))) unsigned int*)g,
      (__attribute__((address_space(3))) unsigned int*)l, 16, 0, 0);
}

__device__ __forceinline__ int xcd_swz(int idx, int nwg) {
  int xcd = idx & 7, pos = idx >> 3;
  int q = nwg >> 3, r = nwg & 7;
  int base = xcd < r ? xcd * (q + 1) : r * (q + 1) + (xcd - r) * q;
  return base + pos;
}

__device__ __forceinline__ unsigned char f2fp8(float v) {
  __hip_fp8_e4m3 h(v);
  return (unsigned char)h.__x;
}
__device__ __forceinline__ float fp82f(unsigned char b) {
  __hip_fp8_e4m3 h;
  h.__x = (__hip_fp8_storage_t)b;
  return (float)h;
}

struct bf16x4s { bf16 a, b, c, d; };

// ---------------- fused prep kernel (conversions + pads + biases + scan) ----------------

#define NB0 4096    // hidden f32 -> hiddenF8 [4096][1024]
#define NB1 10240   // w0+cw -> headwF8 [10240][1024] fp8 (+zero pads)
#define NB2 2528    // w1 -> w1p [10112][256] bf16
#define NB3 1256    // w2 -> w2p [20096][64] bf16
#define NB4 316     // w3 -> w3p [10112][32] bf16 (K pad 16->32)
#define NB5 352     // p0..p3 transpose -> pF8 [1408][1024] fp8
#define NB6 198     // biases (10240+10112+20096+10112 = 50560 elems)
// +1 block: scan_compact (also zeroes counts[0] = merge completion counter)

__global__ __launch_bounds__(256) void prep(
    const float* __restrict__ hidden, const float* __restrict__ w0,
    const float* __restrict__ cw, const float* __restrict__ w1,
    const float* __restrict__ w2, const float* __restrict__ w3,
    const float* __restrict__ p0, const float* __restrict__ p1,
    const float* __restrict__ p2, const float* __restrict__ p3,
    const float* __restrict__ b0, const float* __restrict__ cb,
    const float* __restrict__ b1, const float* __restrict__ b2,
    const float* __restrict__ b3, const int* __restrict__ target,
    unsigned char* __restrict__ hiddenF8, unsigned char* __restrict__ headwF8,
    bf16* __restrict__ w1p, bf16* __restrict__ w2p, bf16* __restrict__ w3p,
    unsigned char* __restrict__ pF8,
    float* __restrict__ headb, float* __restrict__ t1b,
    float* __restrict__ t2b, float* __restrict__ t3b,
    int* __restrict__ r1, int* __restrict__ r2, int* __restrict__ r3,
    int* __restrict__ posmap, int* __restrict__ counts) {
  __shared__ float tile[64][65];
  __shared__ unsigned long long sd[256];
  int b = blockIdx.x, t = threadIdx.x;
  if (b < NB0) {
    long i = (long)b * 256 + t;
    float4 v = ((const float4*)hidden)[i];
    unsigned int u = (unsigned int)f2fp8(v.x) | ((unsigned int)f2fp8(v.y) << 8) |
                     ((unsigned int)f2fp8(v.z) << 16) | ((unsigned int)f2fp8(v.w) << 24);
    ((unsigned int*)hiddenF8)[i] = u;
    return;
  }
  b -= NB0;
  if (b < NB1) {
    long i = (long)b * 256 + t;
    int row = (int)(i >> 8), c4 = ((int)i & 255) * 4;
    float4 v;
    if (row < 10000)      v = *(const float4*)(w0 + (long)row * 1024 + c4);
    else if (row < 10003) v = *(const float4*)(cw + (long)(row - 10000) * 1024 + c4);
    else                  v = make_float4(0.f, 0.f, 0.f, 0.f);
    unsigned int u = (unsigned int)f2fp8(v.x) | ((unsigned int)f2fp8(v.y) << 8) |
                     ((unsigned int)f2fp8(v.z) << 16) | ((unsigned int)f2fp8(v.w) << 24);
    ((unsigned int*)headwF8)[i] = u;
    return;
  }
  b -= NB1;
  if (b < NB2) {
    long i = (long)b * 256 + t;
    int row = (int)(i >> 6), c4 = ((int)i & 63) * 4;
    float4 v = row < 10000 ? *(const float4*)(w1 + (long)row * 256 + c4)
                           : make_float4(0.f, 0.f, 0.f, 0.f);
    bf16x4s o; o.a = (bf16)v.x; o.b = (bf16)v.y; o.c = (bf16)v.z; o.d = (bf16)v.w;
    ((bf16x4s*)w1p)[i] = o;
    return;
  }
  b -= NB2;
  if (b < NB3) {
    long i = (long)b * 256 + t;
    int row = (int)(i >> 4), c4 = ((int)i & 15) * 4;
    float4 v = row < 20000 ? *(const float4*)(w2 + (long)row * 64 + c4)
                           : make_float4(0.f, 0.f, 0.f, 0.f);
    bf16x4s o; o.a = (bf16)v.x; o.b = (bf16)v.y; o.c = (bf16)v.z; o.d = (bf16)v.w;
    ((bf16x4s*)w2p)[i] = o;
    return;
  }
  b -= NB3;
  if (b < NB4) {
    long i = (long)b * 256 + t;
    int row = (int)(i >> 3), c4 = ((int)i & 7) * 4;
    float4 v = (row < 10000 && c4 < 16) ? *(const float4*)(w3 + (long)row * 16 + c4)
                                        : make_float4(0.f, 0.f, 0.f, 0.f);
    bf16x4s o; o.a = (bf16)v.x; o.b = (bf16)v.y; o.c = (bf16)v.z; o.d = (bf16)v.w;
    ((bf16x4s*)w3p)[i] = o;
    return;
  }
  b -= NB4;
  if (b < NB5) {
    int tk = b & 15, tn = b >> 4;
    int kb = tk * 64, nb = tn * 64;
    const float* src; int N, segn;
    if (tn < 16)      { src = p0; N = 1024; segn = nb; }
    else if (tn < 20) { src = p1; N = 256;  segn = nb - 1024; }
    else if (tn < 21) { src = p2; N = 64;   segn = 0; }
    else              { src = p3; N = 16;   segn = 0; }
    int tx = t & 63, ty = t >> 6;
#pragma unroll
    for (int kk = ty; kk < 64; kk += 4)
      tile[kk][tx] = (segn + tx < N) ? src[(long)(kb + kk) * N + segn + tx] : 0.f;
    __syncthreads();
#pragma unroll
    for (int nn = ty; nn < 64; nn += 4)
      pF8[(long)(nb + nn) * 1024 + kb + tx] = f2fp8(tile[tx][nn]);
    return;
  }
  b -= NB5;
  if (b < NB6) {
    int i = b * 256 + t;
    if (i < 10240) {
      headb[i] = i < 10000 ? b0[i] : (i < 10003 ? cb[i - 10000] : -3.0e38f);
    } else if (i < 10240 + 10112) {
      int j = i - 10240; t1b[j] = j < 10000 ? b1[j] : -3.0e38f;
    } else if (i < 10240 + 10112 + 20096) {
      int j = i - 10240 - 10112; t2b[j] = j < 20000 ? b2[j] : -3.0e38f;
    } else if (i < 10240 + 10112 + 20096 + 10112) {
      int j = i - 10240 - 10112 - 20096; t3b[j] = j < 10000 ? b3[j] : -3.0e38f;
    }
    return;
  }
  // ---- scan_compact segment (1 block) ----
  {
    int c1 = 0, c2 = 0, c3 = 0;
#pragma unroll
    for (int j = 0; j < 16; ++j) {
      int tt = target[t * 16 + j];
      if (tt >= 10000) { if (tt < 20000) ++c1; else if (tt < 40000) ++c2; else ++c3; }
    }
    unsigned long long packed = (unsigned long long)c1 |
                                ((unsigned long long)c2 << 21) |
                                ((unsigned long long)c3 << 42);
    sd[t] = packed;
    __syncthreads();
    for (int off = 1; off < 256; off <<= 1) {
      unsigned long long add = t >= off ? sd[t - off] : 0ULL;
      __syncthreads();
      sd[t] += add;
      __syncthreads();
    }
    unsigned long long excl = sd[t] - packed;
    const unsigned long long M21 = (1ULL << 21) - 1;
    int p1i = (int)(excl & M21), p2i = (int)((excl >> 21) & M21), p3i = (int)(excl >> 42);
#pragma unroll
    for (int j = 0; j < 16; ++j) {
      int row = t * 16 + j;
      int tt = target[row];
      if (tt >= 10000) {
        if (tt < 20000)      { r1[p1i] = row; posmap[row] = p1i; ++p1i; }
        else if (tt < 40000) { r2[p2i] = row; posmap[row] = p2i; ++p2i; }
        else                 { r3[p3i] = row; posmap[row] = p3i; ++p3i; }
      }
    }
    if (t == 255) {
      unsigned long long tot = sd[255];
      counts[0] = 0;   // merge_lp completion counter (reset each call)
      counts[1] = (int)(tot & M21);
      counts[2] = (int)((tot >> 21) & M21);
      counts[3] = (int)(tot >> 42);
    }
  }
}

// ---------------- fp8 staged 128x128 GEMM, K=1024, BK=64, 4 blocks/CU ----------------
// 4 waves 2x2; wave = 64x64 = 2x2 of mfma_scale_f32_32x32x64_f8f6f4 (scales=1).
// Counted-vmcnt dbuf (r8 sync structure, verified): stage(buf^1) 4 gl_lds,
// s_waitcnt vmcnt(4) waits only for buf[cur], raw s_barrier, compute, barrier.
// BK=64 halves LDS to 32KB -> 4 blocks/CU (16 waves) for stall hiding.
// 2-bit XOR slot swizzle on 64B LDS rows (round-4-verified layout).
// XCD mapping: xcd = bid&7 owns 4 row panels (L2-resident); streams tiles.
// MODE 0: LDS-repack epilogue -> coalesced stores.  MODE 1: fixed-ref LSE.
// !! CLIFF-SENSITIVE (r10/r11 lesson): do not modify this kernel's source !!

template<int MODE>
__global__ __launch_bounds__(256, 4) void f8gemm(
    const unsigned char* __restrict__ A,
    const unsigned char* __restrict__ B,
    unsigned char* __restrict__ Cf8, bf16* __restrict__ Cbf,
    const float* __restrict__ bias,
    float* __restrict__ Ps, int nslot) {
  int bid = blockIdx.x;
  int xcd = bid & 7, pos = bid >> 3;
  int tile = pos >> 2;
  int rowblk = (xcd << 2) | (pos & 3);
  int rowbase = rowblk * 128;
  int tid = threadIdx.x;
  int w = tid >> 6, l = tid & 63;
  int l31 = l & 31, lh = l >> 5;
  int wr = w >> 1, wc = w & 1;

  // layout: As0(8K) As1(8K) Bs0(8K) Bs1(8K) -- contiguous 32KB for epilogue reuse
  __shared__ __align__(16) unsigned char SMEM[32768];

  // staging: thread t covers 16B slot (t&3) of row (t>>2) in each 64-row half.
  // LDS[row][s] = G[row][s ^ f2(row)], f2(r) = (r ^ (r>>2)) & 3.
  int srow = tid >> 2;
  int slot = tid & 3;
  const unsigned char* ga[2];
  const unsigned char* gb[2];
#pragma unroll
  for (int c = 0; c < 2; ++c) {
    int lrow = c * 64 + srow;
    int gslot = slot ^ ((lrow ^ (lrow >> 2)) & 3);
    ga[c] = A + (long)(rowbase + lrow) * 1024 + gslot * 16;
    gb[c] = B + (long)(tile * 128 + lrow) * 1024 + gslot * 16;
  }

  f32x16 acc[2][2];
#pragma unroll
  for (int m = 0; m < 2; ++m)
#pragma unroll
    for (int n = 0; n < 2; ++n)
#pragma unroll
      for (int g = 0; g < 16; ++g) acc[m][n][g] = 0.f;

  // prologue: stage k0=0 into buf 0 (4 gl_lds per thread)
#pragma unroll
  for (int c = 0; c < 2; ++c) {
    gl_lds16(ga[c], SMEM + c * 4096 + tid * 16);
    gl_lds16(gb[c], SMEM + 16384 + c * 4096 + tid * 16);
  }

  int cur = 0;
#pragma unroll
  for (int i = 0; i < 16; ++i) {
    if (i < 15) {
      int nxt = cur ^ 1;
      int k0 = (i + 1) * 64;
#pragma unroll
      for (int c = 0; c < 2; ++c) {
        gl_lds16(ga[c] + k0, SMEM + nxt * 8192 + c * 4096 + tid * 16);
        gl_lds16(gb[c] + k0, SMEM + 16384 + nxt * 8192 + c * 4096 + tid * 16);
      }
      // wait only for buf[cur]'s 4 loads; the 4 just issued stay in flight
      asm volatile("s_waitcnt vmcnt(4)" ::: "memory");
    } else {
      asm volatile("s_waitcnt vmcnt(0)" ::: "memory");
    }
    __builtin_amdgcn_s_barrier();
    __builtin_amdgcn_sched_barrier(0);

    const unsigned char* Ab = SMEM + cur * 8192;
    const unsigned char* Bb = SMEM + 16384 + cur * 8192;
    i32x8 af[2], bfr[2];
#pragma unroll
    for (int m = 0; m < 2; ++m) {
      int ar = wr * 64 + m * 32 + l31;
      int f = (ar ^ (ar >> 2)) & 3;
      int s0 = (lh * 2) ^ f;
      int s1 = (lh * 2 + 1) ^ f;
      int4 lo = *(const int4*)(Ab + ar * 64 + s0 * 16);
      int4 hi = *(const int4*)(Ab + ar * 64 + s1 * 16);
      af[m][0] = lo.x; af[m][1] = lo.y; af[m][2] = lo.z; af[m][3] = lo.w;
      af[m][4] = hi.x; af[m][5] = hi.y; af[m][6] = hi.z; af[m][7] = hi.w;
    }
#pragma unroll
    for (int n = 0; n < 2; ++n) {
      int br = wc * 64 + n * 32 + l31;
      int f = (br ^ (br >> 2)) & 3;
      int s0 = (lh * 2) ^ f;
      int s1 = (lh * 2 + 1) ^ f;
      int4 lo = *(const int4*)(Bb + br * 64 + s0 * 16);
      int4 hi = *(const int4*)(Bb + br * 64 + s1 * 16);
      bfr[n][0] = lo.x; bfr[n][1] = lo.y; bfr[n][2] = lo.z; bfr[n][3] = lo.w;
      bfr[n][4] = hi.x; bfr[n][5] = hi.y; bfr[n][6] = hi.z; bfr[n][7] = hi.w;
    }
#pragma unroll
    for (int m = 0; m < 2; ++m)
#pragma unroll
      for (int n = 0; n < 2; ++n)
        acc[m][n] = __builtin_amdgcn_mfma_scale_f32_32x32x64_f8f6f4(
            af[m], bfr[n], acc[m][n], 0, 0, 0, 0x7F7F7F7F, 0, 0x7F7F7F7F);
    // all ds_reads of buf[cur] complete (lgkmcnt waits precede the MFMAs);
    // this barrier makes it safe for the next iteration to overwrite buf[cur].
    __builtin_amdgcn_s_barrier();
    cur ^= 1;
  }
  __builtin_amdgcn_sched_barrier(0);

  if (MODE == 0) {
    // LDS-repack epilogue: acc -> SMEM -> coalesced 16B stores.
    int col0 = tile * 128;
    if (col0 < 1024) {
      // fp8 out: 128x128 bytes = 16KB in LDS
#pragma unroll
      for (int m = 0; m < 2; ++m)
#pragma unroll
        for (int n = 0; n < 2; ++n) {
          int col = wc * 64 + n * 32 + l31;
#pragma unroll
          for (int g = 0; g < 16; ++g) {
            int row = wr * 64 + m * 32 + (g & 3) + 8 * (g >> 2) + 4 * lh;
            SMEM[row * 128 + col] = f2fp8(acc[m][n][g]);
          }
        }
      __syncthreads();
      int row = tid >> 1, half = tid & 1;
      unsigned char* gp = Cf8 + (long)(rowbase + row) * 1024 + col0 + half * 64;
#pragma unroll
      for (int j = 0; j < 4; ++j)
        *(int4*)(gp + j * 16) = *(const int4*)(SMEM + tid * 64 + j * 16);
    } else {
      // bf16 out: 128x128 x2B = 32KB in LDS
      bf16* Lb = (bf16*)SMEM;
#pragma unroll
      for (int m = 0; m < 2; ++m)
#pragma unroll
        for (int n = 0; n < 2; ++n) {
          int col = wc * 64 + n * 32 + l31;
#pragma unroll
          for (int g = 0; g < 16; ++g) {
            int row = wr * 64 + m * 32 + (g & 3) + 8 * (g >> 2) + 4 * lh;
            Lb[row * 128 + col] = (bf16)acc[m][n][g];
          }
        }
      __syncthreads();
      int row = tid >> 1, half = tid & 1;
      bf16* gp = Cbf + (long)(rowbase + row) * 384 + (col0 - 1024) + half * 64;
#pragma unroll
      for (int j = 0; j < 8; ++j)
        *(int4*)(gp + j * 8) = *(const int4*)(SMEM + tid * 128 + j * 16);
    }
  } else {
    float rs[2][16];
#pragma unroll
    for (int m = 0; m < 2; ++m)
#pragma unroll
      for (int g = 0; g < 16; ++g) rs[m][g] = 0.f;
    int col0 = tile * 128;
#pragma unroll
    for (int n = 0; n < 2; ++n) {
      float bv = bias[col0 + wc * 64 + n * 32 + l31];
#pragma unroll
      for (int m = 0; m < 2; ++m)
#pragma unroll
        for (int g = 0; g < 16; ++g)
          rs[m][g] += __expf(acc[m][n][g] + bv - MREF);
    }
#pragma unroll
    for (int m = 0; m < 2; ++m)
#pragma unroll
      for (int g = 0; g < 16; ++g) {
        float v = rs[m][g];
        v += __shfl_xor(v, 1);
        v += __shfl_xor(v, 2);
        v += __shfl_xor(v, 4);
        v += __shfl_xor(v, 8);
        v += __shfl_xor(v, 16);
        rs[m][g] = v;
      }
    if (l31 == 0) {
      int slotP = tile * 2 + wc;
#pragma unroll
      for (int m = 0; m < 2; ++m)
#pragma unroll
        for (int g = 0; g < 16; ++g) {
          int row = rowbase + wr * 64 + m * 32 + (g & 3) + 8 * (g >> 2) + 4 * lh;
          Ps[(long)row * nslot + slotP] = rs[m][g];
        }
    }
  }
}

// ---------------- bf16 tail body: 128x128 staged + fixed-ref LSE (gathered rows) ----------------

template<int K>
__device__ __forceinline__ void tail_body(
    int wg, const bf16* __restrict__ A, int lda,
    const bf16* __restrict__ B, int nTiles, int tpb,
    const float* __restrict__ bias,
    float* __restrict__ Ps, int nslot,
    const int* __restrict__ rowidx, const int* __restrict__ counts, int cluster,
    bf16* As, bf16* Bs) {
  int split = wg >> 5;
  int rowblk = wg & 31;
  int rowbase = rowblk * 128;
  int nc = counts[cluster];
  if (rowbase >= nc) return;   // block-uniform exit, before any barrier
  int tid = threadIdx.x;
  int w = tid >> 6, llo = tid & 15, lhi = (tid >> 4) & 3;
  int wr = w >> 1, wc = w & 1;

  int srow = tid >> 2;
  int selem = (tid & 3) * 8;
  int sr0 = rowbase + srow, sr1 = sr0 + 64;
  sr0 = rowidx[sr0 < nc ? sr0 : nc - 1];
  sr1 = rowidx[sr1 < nc ? sr1 : nc - 1];
  const bf16* ga0 = A + (long)sr0 * lda + selem;
  const bf16* ga1 = A + (long)sr1 * lda + selem;
  bf16* la0 = As + tid * 8;
  bf16* la1 = As + 2048 + tid * 8;
  bf16* lb0 = Bs + tid * 8;
  bf16* lb1 = Bs + 2048 + tid * 8;

  float rs[4][4];
#pragma unroll
  for (int a = 0; a < 4; ++a)
#pragma unroll
    for (int bq = 0; bq < 4; ++bq) rs[a][bq] = 0.f;

  int t0 = split * tpb;
  int tE = t0 + tpb; if (tE > nTiles) tE = nTiles;

  for (int tile = t0; tile < tE; ++tile) {
    int col0 = tile * 128;
    const bf16* gb0 = B + (long)(col0 + srow) * K + selem;
    const bf16* gb1 = gb0 + (long)64 * K;

    f32x4 acc[4][4];
    f32x4 zero = {0.f, 0.f, 0.f, 0.f};
#pragma unroll
    for (int a = 0; a < 4; ++a)
#pragma unroll
      for (int bq = 0; bq < 4; ++bq) acc[a][bq] = zero;

    for (int k0 = 0; k0 < K; k0 += 32) {
      gl_lds16(ga0 + k0, la0);
      gl_lds16(ga1 + k0, la1);
      gl_lds16(gb0 + k0, lb0);
      gl_lds16(gb1 + k0, lb1);
      __syncthreads();
      bf16x8 af[4], bf_[4];
#pragma unroll
      for (int m = 0; m < 4; ++m)
        af[m] = *(const bf16x8*)(As + (wr * 64 + m * 16 + llo) * 32 + lhi * 8);
#pragma unroll
      for (int n = 0; n < 4; ++n)
        bf_[n] = *(const bf16x8*)(Bs + (wc * 64 + n * 16 + llo) * 32 + lhi * 8);
#pragma unroll
      for (int m = 0; m < 4; ++m)
#pragma unroll
        for (int n = 0; n < 4; ++n)
          acc[m][n] = __builtin_amdgcn_mfma_f32_16x16x32_bf16(af[m], bf_[n], acc[m][n], 0, 0, 0);
      __syncthreads();
    }

    float bv[4];
#pragma unroll
    for (int n = 0; n < 4; ++n) bv[n] = bias[col0 + wc * 64 + n * 16 + llo];
#pragma unroll
    for (int mm = 0; mm < 4; ++mm)
#pragma unroll
      for (int r = 0; r < 4; ++r)
#pragma unroll
        for (int n = 0; n < 4; ++n)
          rs[mm][r] += __expf(acc[mm][n][r] + bv[n] - MREF);
  }

#pragma unroll
  for (int mm = 0; mm < 4; ++mm) {
#pragma unroll
    for (int r = 0; r < 4; ++r) {
      float vv = rs[mm][r];
      vv += __shfl_xor(vv, 1);
      vv += __shfl_xor(vv, 2);
      vv += __shfl_xor(vv, 4);
      vv += __shfl_xor(vv, 8);
      if (llo == 0) {
        int crow = rowbase + wr * 64 + mm * 16 + lhi * 4 + r;
        Ps[(long)crow * nslot + (split * 2 + wc)] = vv;
      }
    }
  }
}

// ---------------- fused tails kernel: 3 independent clusters, one launch ----------------

#define TAIL_NWG 2528

__global__ __launch_bounds__(256, 3) void tails(
    const bf16* __restrict__ projT,
    const bf16* __restrict__ w1p, const float* __restrict__ t1b,
    float* __restrict__ s1P, const int* __restrict__ r1,
    const bf16* __restrict__ w2p, const float* __restrict__ t2b,
    float* __restrict__ s2P, const int* __restrict__ r2,
    const bf16* __restrict__ w3p, const float* __restrict__ t3b,
    float* __restrict__ s3P, const int* __restrict__ r3,
    const int* __restrict__ counts) {
  __shared__ __align__(16) bf16 As[128 * 32];
  __shared__ __align__(16) bf16 Bs[128 * 32];
  int b = blockIdx.x;
  if (b < TAIL_NWG) {
    tail_body<256>(xcd_swz(b, TAIL_NWG), projT, 384, w1p, 79, 1,
                   t1b, s1P, 158, r1, counts, 1, As, Bs);
    return;
  }
  b -= TAIL_NWG;
  if (b < TAIL_NWG) {
    tail_body<64>(xcd_swz(b, TAIL_NWG), projT + 256, 384, w2p, 157, 2,
                  t2b, s2P, 158, r2, counts, 2, As, Bs);
    return;
  }
  b -= TAIL_NWG;
  tail_body<32>(xcd_swz(b, TAIL_NWG), projT + 320, 384, w3p, 79, 1,
                t3b, s3P, 158, r3, counts, 3, As, Bs);
}

// ---------------- merge partials + gathers -> lp, + fused last-block reduce ----------------
// SLIM (r14-verified): one fp8 head dot per row. Fused neg_mean: each block
// bumps counts[0] after threadfence; the last block re-reads lp in fixed
// tid-strided order (deterministic) and writes the scalar output.

__global__ __launch_bounds__(256) void merge_lp(
    const int* __restrict__ target, const int* __restrict__ posmap,
    const unsigned char* __restrict__ projF8, const unsigned char* __restrict__ headw,
    const float* __restrict__ headb, const bf16* __restrict__ projT,
    const bf16* __restrict__ w1p, const float* __restrict__ t1b,
    const bf16* __restrict__ w2p, const float* __restrict__ t2b,
    const bf16* __restrict__ w3p, const float* __restrict__ t3b,
    const float* __restrict__ hs, int NSH,
    const float* __restrict__ s1, int NS1,
    const float* __restrict__ s2, int NS2,
    const float* __restrict__ s3, int NS3,
    float* __restrict__ lp, int* __restrict__ ctr, float* __restrict__ out) {
  int lane = threadIdx.x & 63;
  int row = (blockIdx.x * 256 + threadIdx.x) >> 6;

  // head logsumexp from partial slots
  float sh = 0.f;
  for (int sp = lane; sp < NSH; sp += 64) sh += hs[(long)row * NSH + sp];
#pragma unroll
  for (int off = 1; off < 64; off <<= 1) sh += __shfl_xor(sh, off);
  float lseh = MREF + __logf(sh);

  int t = target[row];
  int q = t < 10000 ? 0 : (t < 20000 ? 3 : (t < 40000 ? 2 : 1));
  int col = t < 10000 ? t : 9999 + q;

  // single head dot (fp8 K=1024) at col
  const unsigned char* ap = projF8 + (long)row * 1024 + lane * 16;
  const unsigned char* wp = headw + (long)col * 1024 + lane * 16;
  float d = 0.f;
#pragma unroll
  for (int j = 0; j < 16; ++j) d += fp82f(ap[j]) * fp82f(wp[j]);
#pragma unroll
  for (int off = 1; off < 64; off <<= 1) d += __shfl_xor(d, off);
  float hd = d + headb[col];

  float res;
  if (t < 10000) {
    res = hd - lseh;
  } else {
    const float* sP; const bf16* wP; const float* bP;
    int NS, Kt, offT, base;
    if (t < 20000)      { sP = s1; wP = w1p; bP = t1b; NS = NS1; Kt = 256; offT = 0;   base = 10000; }
    else if (t < 40000) { sP = s2; wP = w2p; bP = t2b; NS = NS2; Kt = 64;  offT = 256; base = 20000; }
    else                { sP = s3; wP = w3p; bP = t3b; NS = NS3; Kt = 32;  offT = 320; base = 40000; }
    int pos = posmap[row];
    float ss = 0.f;
    for (int sp = lane; sp < NS; sp += 64) ss += sP[(long)pos * NS + sp];
#pragma unroll
    for (int off = 1; off < 64; off <<= 1) ss += __shfl_xor(ss, off);
    float lset = MREF + __logf(ss);
    int wrow = t - base;
    float gt = 0.f;
    for (int k = lane; k < Kt; k += 64)
      gt += (float)projT[(long)row * 384 + offT + k] * (float)wP[(long)wrow * Kt + k];
#pragma unroll
    for (int off = 1; off < 64; off <<= 1) gt += __shfl_xor(gt, off);
    gt += bP[wrow];
    res = (hd - lseh) + (gt - lset);
  }
  if (lane == 0) lp[row] = res;

  // fused reduction: last block to finish sums lp (fixed order -> deterministic)
  __syncthreads();
  __shared__ int isLast;
  if (threadIdx.x == 0) {
    __threadfence();
    isLast = (atomicAdd(ctr, 1) == (int)gridDim.x - 1) ? 1 : 0;
  }
  __syncthreads();
  if (isLast) {
    __threadfence();
    __shared__ float red[256];
    float s = 0.f;
    for (int i = threadIdx.x; i < M_TOK; i += 256) s += lp[i];
    red[threadIdx.x] = s;
    __syncthreads();
    for (int o = 128; o > 0; o >>= 1) {
      if (threadIdx.x < o) red[threadIdx.x] += red[threadIdx.x + o];
      __syncthreads();
    }
    if (threadIdx.x == 0) out[0] = -red[0] / (float)M_TOK;
  }
}

// ---------------- host ----------------

extern "C" void kernel_launch(void* const* d_in, const int* in_sizes, int n_in,
                              void* d_out, int out_size, void* d_ws, size_t ws_size,
                              hipStream_t stream) {
  const float* hidden = (const float*)d_in[0];
  const int*   target = (const int*)d_in[1];
  const float* w0 = (const float*)d_in[2];
  const float* b0 = (const float*)d_in[3];
  const float* p0 = (const float*)d_in[4];
  const float* w1 = (const float*)d_in[5];
  const float* b1 = (const float*)d_in[6];
  const float* p1 = (const float*)d_in[7];
  const float* w2 = (const float*)d_in[8];
  const float* b2 = (const float*)d_in[9];
  const float* p2 = (const float*)d_in[10];
  const float* w3 = (const float*)d_in[11];
  const float* b3 = (const float*)d_in[12];
  const float* p3 = (const float*)d_in[13];
  const float* cw = (const float*)d_in[14];
  const float* cb = (const float*)d_in[15];

  const int NH = 10240;                       // head cols (128-padded)
  const int N1 = 10112, N2 = 20096, N3 = 10112;
  const int TH = NH / 128;                    // 80
  const int NSH = TH * 2, NS1 = 158, NS2 = 158, NS3 = 158;

  char* ws = (char*)d_ws;
  size_t off = 0;
  auto alloc = [&](size_t bytes) -> char* {
    char* p = ws + off;
    off += (bytes + 255) & ~(size_t)255;
    return p;
  };
  unsigned char* hiddenF8 = (unsigned char*)alloc(4096L * 1024);
  unsigned char* pF8      = (unsigned char*)alloc(1408L * 1024);
  unsigned char* headwF8  = (unsigned char*)alloc((long)NH * 1024);
  bf16* w1p   = (bf16*)alloc((long)N1 * 256 * 2);
  bf16* w2p   = (bf16*)alloc((long)N2 * 64 * 2);
  bf16* w3p   = (bf16*)alloc((long)N3 * 32 * 2);
  unsigned char* projF8 = (unsigned char*)alloc(4096L * 1024);
  bf16* projT = (bf16*)alloc(4096L * 384 * 2);
  float* headb = (float*)alloc((long)NH * 4);
  float* t1b   = (float*)alloc((long)N1 * 4);
  float* t2b   = (float*)alloc((long)N2 * 4);
  float* t3b   = (float*)alloc((long)N3 * 4);
  float* hsP = (float*)alloc((size_t)M_TOK * NSH * 4);
  float* s1P = (float*)alloc((size_t)M_TOK * NS1 * 4);
  float* s2P = (float*)alloc((size_t)M_TOK * NS2 * 4);
  float* s3P = (float*)alloc((size_t)M_TOK * NS3 * 4);
  float* lp  = (float*)alloc((size_t)M_TOK * 4);
  int* r1 = (int*)alloc((size_t)M_TOK * 4);
  int* r2 = (int*)alloc((size_t)M_TOK * 4);
  int* r3 = (int*)alloc((size_t)M_TOK * 4);
  int* posmap = (int*)alloc((size_t)M_TOK * 4);
  int* counts = (int*)alloc(16);
  if (ws_size < off) return;  // fail cleanly rather than corrupt

  // 1) fused prep: all conversions, transposes, pads, biases, compaction scan
  const int PREP_BLOCKS = NB0 + NB1 + NB2 + NB3 + NB4 + NB5 + NB6 + 1;
  prep<<<PREP_BLOCKS, 256, 0, stream>>>(
      hidden, w0, cw, w1, w2, w3, p0, p1, p2, p3, b0, cb, b1, b2, b3, target,
      hiddenF8, headwF8, w1p, w2p, w3p, pF8, headb, t1b, t2b, t3b,
      r1, r2, r3, posmap, counts);

  // 2) projection (fp8 MX): proj = hiddenF8 @ pF8^T ; cols<1024 -> fp8, rest -> bf16
  f8gemm<0><<<11 * 32, 256, 0, stream>>>(
      hiddenF8, pF8, projF8, projT, nullptr, nullptr, 0);

  // 3) head logits + fixed-ref LSE partials (fp8 MX, BK=64, counted-vmcnt dbuf)
  f8gemm<1><<<TH * 32, 256, 0, stream>>>(
      projF8, headwF8, nullptr, nullptr, headb, hsP, NSH);

  // 4) fused tails: all three clusters in one launch (disjoint outputs)
  tails<<<3 * TAIL_NWG, 256, 0, stream>>>(
      projT, w1p, t1b, s1P, r1, w2p, t2b, s2P, r2, w3p, t3b, s3P, r3, counts);

  // 5) merge partials + gathers -> lp, fused last-block reduction -> d_out
  merge_lp<<<1024, 256, 0, stream>>>(
      target, posmap, projF8, headwF8, headb, projT,
      w1p, t1b, w2p, t2b, w3p, t3b,
      hsP, NSH, s1P, NS1, s2P, NS2, s3P, NS3, lp, counts, (float*)d_out);
}

// Round 17
// 138.098 us; speedup vs baseline: 1.1321x; 1.1321x over previous
//
#include <hip/hip_runtime.h>
#include <hip/hip_fp8.h>
#include <math.h>

typedef __bf16 bf16;
typedef __attribute__((ext_vector_type(8))) __bf16 bf16x8;
typedef __attribute__((ext_vector_type(4))) float f32x4;
typedef __attribute__((ext_vector_type(16))) float f32x16;
typedef __attribute__((ext_vector_type(8))) int i32x8;

#define M_TOK 4096
#define MREF 8.0f   // fixed logsumexp reference (logits bounded ~|4|)

// ---------------- helpers ----------------

__device__ __forceinline__ void gl_lds16(const void* g, void* l) {
  __builtin_amdgcn_global_load_lds(
      (const __attribute__((address_space(1))) unsigned int*)g,
      (__attribute__((address_space(3))) unsigned int*)l, 16, 0, 0);
}

__device__ __forceinline__ int xcd_swz(int idx, int nwg) {
  int xcd = idx & 7, pos = idx >> 3;
  int q = nwg >> 3, r = nwg & 7;
  int base = xcd < r ? xcd * (q + 1) : r * (q + 1) + (xcd - r) * q;
  return base + pos;
}

__device__ __forceinline__ unsigned char f2fp8(float v) {
  __hip_fp8_e4m3 h(v);
  return (unsigned char)h.__x;
}
__device__ __forceinline__ float fp82f(unsigned char b) {
  __hip_fp8_e4m3 h;
  h.__x = (__hip_fp8_storage_t)b;
  return (float)h;
}

struct bf16x4s { bf16 a, b, c, d; };

// ---------------- fused prep kernel (conversions + pads + biases + scan) ----------------

#define NB0 4096    // hidden f32 -> hiddenF8 [4096][1024]
#define NB1 10240   // w0+cw -> headwF8 [10240][1024] fp8 (+zero pads)
#define NB2 2528    // w1 -> w1p [10112][256] bf16
#define NB3 1256    // w2 -> w2p [20096][64] bf16
#define NB4 316     // w3 -> w3p [10112][32] bf16 (K pad 16->32)
#define NB5 352     // p0..p3 transpose -> pF8 [1408][1024] fp8
#define NB6 198     // biases (10240+10112+20096+10112 = 50560 elems)
// +1 block: scan_compact

__global__ __launch_bounds__(256) void prep(
    const float* __restrict__ hidden, const float* __restrict__ w0,
    const float* __restrict__ cw, const float* __restrict__ w1,
    const float* __restrict__ w2, const float* __restrict__ w3,
    const float* __restrict__ p0, const float* __restrict__ p1,
    const float* __restrict__ p2, const float* __restrict__ p3,
    const float* __restrict__ b0, const float* __restrict__ cb,
    const float* __restrict__ b1, const float* __restrict__ b2,
    const float* __restrict__ b3, const int* __restrict__ target,
    unsigned char* __restrict__ hiddenF8, unsigned char* __restrict__ headwF8,
    bf16* __restrict__ w1p, bf16* __restrict__ w2p, bf16* __restrict__ w3p,
    unsigned char* __restrict__ pF8,
    float* __restrict__ headb, float* __restrict__ t1b,
    float* __restrict__ t2b, float* __restrict__ t3b,
    int* __restrict__ r1, int* __restrict__ r2, int* __restrict__ r3,
    int* __restrict__ posmap, int* __restrict__ counts) {
  __shared__ float tile[64][65];
  __shared__ unsigned long long sd[256];
  int b = blockIdx.x, t = threadIdx.x;
  if (b < NB0) {
    long i = (long)b * 256 + t;
    float4 v = ((const float4*)hidden)[i];
    unsigned int u = (unsigned int)f2fp8(v.x) | ((unsigned int)f2fp8(v.y) << 8) |
                     ((unsigned int)f2fp8(v.z) << 16) | ((unsigned int)f2fp8(v.w) << 24);
    ((unsigned int*)hiddenF8)[i] = u;
    return;
  }
  b -= NB0;
  if (b < NB1) {
    long i = (long)b * 256 + t;
    int row = (int)(i >> 8), c4 = ((int)i & 255) * 4;
    float4 v;
    if (row < 10000)      v = *(const float4*)(w0 + (long)row * 1024 + c4);
    else if (row < 10003) v = *(const float4*)(cw + (long)(row - 10000) * 1024 + c4);
    else                  v = make_float4(0.f, 0.f, 0.f, 0.f);
    unsigned int u = (unsigned int)f2fp8(v.x) | ((unsigned int)f2fp8(v.y) << 8) |
                     ((unsigned int)f2fp8(v.z) << 16) | ((unsigned int)f2fp8(v.w) << 24);
    ((unsigned int*)headwF8)[i] = u;
    return;
  }
  b -= NB1;
  if (b < NB2) {
    long i = (long)b * 256 + t;
    int row = (int)(i >> 6), c4 = ((int)i & 63) * 4;
    float4 v = row < 10000 ? *(const float4*)(w1 + (long)row * 256 + c4)
                           : make_float4(0.f, 0.f, 0.f, 0.f);
    bf16x4s o; o.a = (bf16)v.x; o.b = (bf16)v.y; o.c = (bf16)v.z; o.d = (bf16)v.w;
    ((bf16x4s*)w1p)[i] = o;
    return;
  }
  b -= NB2;
  if (b < NB3) {
    long i = (long)b * 256 + t;
    int row = (int)(i >> 4), c4 = ((int)i & 15) * 4;
    float4 v = row < 20000 ? *(const float4*)(w2 + (long)row * 64 + c4)
                           : make_float4(0.f, 0.f, 0.f, 0.f);
    bf16x4s o; o.a = (bf16)v.x; o.b = (bf16)v.y; o.c = (bf16)v.z; o.d = (bf16)v.w;
    ((bf16x4s*)w2p)[i] = o;
    return;
  }
  b -= NB3;
  if (b < NB4) {
    long i = (long)b * 256 + t;
    int row = (int)(i >> 3), c4 = ((int)i & 7) * 4;
    float4 v = (row < 10000 && c4 < 16) ? *(const float4*)(w3 + (long)row * 16 + c4)
                                        : make_float4(0.f, 0.f, 0.f, 0.f);
    bf16x4s o; o.a = (bf16)v.x; o.b = (bf16)v.y; o.c = (bf16)v.z; o.d = (bf16)v.w;
    ((bf16x4s*)w3p)[i] = o;
    return;
  }
  b -= NB4;
  if (b < NB5) {
    int tk = b & 15, tn = b >> 4;
    int kb = tk * 64, nb = tn * 64;
    const float* src; int N, segn;
    if (tn < 16)      { src = p0; N = 1024; segn = nb; }
    else if (tn < 20) { src = p1; N = 256;  segn = nb - 1024; }
    else if (tn < 21) { src = p2; N = 64;   segn = 0; }
    else              { src = p3; N = 16;   segn = 0; }
    int tx = t & 63, ty = t >> 6;
#pragma unroll
    for (int kk = ty; kk < 64; kk += 4)
      tile[kk][tx] = (segn + tx < N) ? src[(long)(kb + kk) * N + segn + tx] : 0.f;
    __syncthreads();
#pragma unroll
    for (int nn = ty; nn < 64; nn += 4)
      pF8[(long)(nb + nn) * 1024 + kb + tx] = f2fp8(tile[tx][nn]);
    return;
  }
  b -= NB5;
  if (b < NB6) {
    int i = b * 256 + t;
    if (i < 10240) {
      headb[i] = i < 10000 ? b0[i] : (i < 10003 ? cb[i - 10000] : -3.0e38f);
    } else if (i < 10240 + 10112) {
      int j = i - 10240; t1b[j] = j < 10000 ? b1[j] : -3.0e38f;
    } else if (i < 10240 + 10112 + 20096) {
      int j = i - 10240 - 10112; t2b[j] = j < 20000 ? b2[j] : -3.0e38f;
    } else if (i < 10240 + 10112 + 20096 + 10112) {
      int j = i - 10240 - 10112 - 20096; t3b[j] = j < 10000 ? b3[j] : -3.0e38f;
    }
    return;
  }
  // ---- scan_compact segment (1 block) ----
  {
    int c1 = 0, c2 = 0, c3 = 0;
#pragma unroll
    for (int j = 0; j < 16; ++j) {
      int tt = target[t * 16 + j];
      if (tt >= 10000) { if (tt < 20000) ++c1; else if (tt < 40000) ++c2; else ++c3; }
    }
    unsigned long long packed = (unsigned long long)c1 |
                                ((unsigned long long)c2 << 21) |
                                ((unsigned long long)c3 << 42);
    sd[t] = packed;
    __syncthreads();
    for (int off = 1; off < 256; off <<= 1) {
      unsigned long long add = t >= off ? sd[t - off] : 0ULL;
      __syncthreads();
      sd[t] += add;
      __syncthreads();
    }
    unsigned long long excl = sd[t] - packed;
    const unsigned long long M21 = (1ULL << 21) - 1;
    int p1i = (int)(excl & M21), p2i = (int)((excl >> 21) & M21), p3i = (int)(excl >> 42);
#pragma unroll
    for (int j = 0; j < 16; ++j) {
      int row = t * 16 + j;
      int tt = target[row];
      if (tt >= 10000) {
        if (tt < 20000)      { r1[p1i] = row; posmap[row] = p1i; ++p1i; }
        else if (tt < 40000) { r2[p2i] = row; posmap[row] = p2i; ++p2i; }
        else                 { r3[p3i] = row; posmap[row] = p3i; ++p3i; }
      }
    }
    if (t == 255) {
      unsigned long long tot = sd[255];
      counts[1] = (int)(tot & M21);
      counts[2] = (int)((tot >> 21) & M21);
      counts[3] = (int)(tot >> 42);
    }
  }
}

// ---------------- fp8 staged 128x128 GEMM, K=1024, BK=64, 4 blocks/CU ----------------
// 4 waves 2x2; wave = 64x64 = 2x2 of mfma_scale_f32_32x32x64_f8f6f4 (scales=1).
// Counted-vmcnt dbuf (r8 sync structure, verified): stage(buf^1) 4 gl_lds,
// s_waitcnt vmcnt(4) waits only for buf[cur], raw s_barrier, compute, barrier.
// BK=64 halves LDS to 32KB -> 4 blocks/CU (16 waves) for stall hiding.
// 2-bit XOR slot swizzle on 64B LDS rows (round-4-verified layout).
// XCD mapping: xcd = bid&7 owns 4 row panels (L2-resident); streams tiles.
// MODE 0: LDS-repack epilogue -> coalesced stores.  MODE 1: fixed-ref LSE.
// !! CLIFF-SENSITIVE (r10/r11 lesson): do not modify this kernel's source !!

template<int MODE>
__global__ __launch_bounds__(256, 4) void f8gemm(
    const unsigned char* __restrict__ A,
    const unsigned char* __restrict__ B,
    unsigned char* __restrict__ Cf8, bf16* __restrict__ Cbf,
    const float* __restrict__ bias,
    float* __restrict__ Ps, int nslot) {
  int bid = blockIdx.x;
  int xcd = bid & 7, pos = bid >> 3;
  int tile = pos >> 2;
  int rowblk = (xcd << 2) | (pos & 3);
  int rowbase = rowblk * 128;
  int tid = threadIdx.x;
  int w = tid >> 6, l = tid & 63;
  int l31 = l & 31, lh = l >> 5;
  int wr = w >> 1, wc = w & 1;

  // layout: As0(8K) As1(8K) Bs0(8K) Bs1(8K) -- contiguous 32KB for epilogue reuse
  __shared__ __align__(16) unsigned char SMEM[32768];

  // staging: thread t covers 16B slot (t&3) of row (t>>2) in each 64-row half.
  // LDS[row][s] = G[row][s ^ f2(row)], f2(r) = (r ^ (r>>2)) & 3.
  int srow = tid >> 2;
  int slot = tid & 3;
  const unsigned char* ga[2];
  const unsigned char* gb[2];
#pragma unroll
  for (int c = 0; c < 2; ++c) {
    int lrow = c * 64 + srow;
    int gslot = slot ^ ((lrow ^ (lrow >> 2)) & 3);
    ga[c] = A + (long)(rowbase + lrow) * 1024 + gslot * 16;
    gb[c] = B + (long)(tile * 128 + lrow) * 1024 + gslot * 16;
  }

  f32x16 acc[2][2];
#pragma unroll
  for (int m = 0; m < 2; ++m)
#pragma unroll
    for (int n = 0; n < 2; ++n)
#pragma unroll
      for (int g = 0; g < 16; ++g) acc[m][n][g] = 0.f;

  // prologue: stage k0=0 into buf 0 (4 gl_lds per thread)
#pragma unroll
  for (int c = 0; c < 2; ++c) {
    gl_lds16(ga[c], SMEM + c * 4096 + tid * 16);
    gl_lds16(gb[c], SMEM + 16384 + c * 4096 + tid * 16);
  }

  int cur = 0;
#pragma unroll
  for (int i = 0; i < 16; ++i) {
    if (i < 15) {
      int nxt = cur ^ 1;
      int k0 = (i + 1) * 64;
#pragma unroll
      for (int c = 0; c < 2; ++c) {
        gl_lds16(ga[c] + k0, SMEM + nxt * 8192 + c * 4096 + tid * 16);
        gl_lds16(gb[c] + k0, SMEM + 16384 + nxt * 8192 + c * 4096 + tid * 16);
      }
      // wait only for buf[cur]'s 4 loads; the 4 just issued stay in flight
      asm volatile("s_waitcnt vmcnt(4)" ::: "memory");
    } else {
      asm volatile("s_waitcnt vmcnt(0)" ::: "memory");
    }
    __builtin_amdgcn_s_barrier();
    __builtin_amdgcn_sched_barrier(0);

    const unsigned char* Ab = SMEM + cur * 8192;
    const unsigned char* Bb = SMEM + 16384 + cur * 8192;
    i32x8 af[2], bfr[2];
#pragma unroll
    for (int m = 0; m < 2; ++m) {
      int ar = wr * 64 + m * 32 + l31;
      int f = (ar ^ (ar >> 2)) & 3;
      int s0 = (lh * 2) ^ f;
      int s1 = (lh * 2 + 1) ^ f;
      int4 lo = *(const int4*)(Ab + ar * 64 + s0 * 16);
      int4 hi = *(const int4*)(Ab + ar * 64 + s1 * 16);
      af[m][0] = lo.x; af[m][1] = lo.y; af[m][2] = lo.z; af[m][3] = lo.w;
      af[m][4] = hi.x; af[m][5] = hi.y; af[m][6] = hi.z; af[m][7] = hi.w;
    }
#pragma unroll
    for (int n = 0; n < 2; ++n) {
      int br = wc * 64 + n * 32 + l31;
      int f = (br ^ (br >> 2)) & 3;
      int s0 = (lh * 2) ^ f;
      int s1 = (lh * 2 + 1) ^ f;
      int4 lo = *(const int4*)(Bb + br * 64 + s0 * 16);
      int4 hi = *(const int4*)(Bb + br * 64 + s1 * 16);
      bfr[n][0] = lo.x; bfr[n][1] = lo.y; bfr[n][2] = lo.z; bfr[n][3] = lo.w;
      bfr[n][4] = hi.x; bfr[n][5] = hi.y; bfr[n][6] = hi.z; bfr[n][7] = hi.w;
    }
#pragma unroll
    for (int m = 0; m < 2; ++m)
#pragma unroll
      for (int n = 0; n < 2; ++n)
        acc[m][n] = __builtin_amdgcn_mfma_scale_f32_32x32x64_f8f6f4(
            af[m], bfr[n], acc[m][n], 0, 0, 0, 0x7F7F7F7F, 0, 0x7F7F7F7F);
    // all ds_reads of buf[cur] complete (lgkmcnt waits precede the MFMAs);
    // this barrier makes it safe for the next iteration to overwrite buf[cur].
    __builtin_amdgcn_s_barrier();
    cur ^= 1;
  }
  __builtin_amdgcn_sched_barrier(0);

  if (MODE == 0) {
    // LDS-repack epilogue: acc -> SMEM -> coalesced 16B stores.
    int col0 = tile * 128;
    if (col0 < 1024) {
      // fp8 out: 128x128 bytes = 16KB in LDS
#pragma unroll
      for (int m = 0; m < 2; ++m)
#pragma unroll
        for (int n = 0; n < 2; ++n) {
          int col = wc * 64 + n * 32 + l31;
#pragma unroll
          for (int g = 0; g < 16; ++g) {
            int row = wr * 64 + m * 32 + (g & 3) + 8 * (g >> 2) + 4 * lh;
            SMEM[row * 128 + col] = f2fp8(acc[m][n][g]);
          }
        }
      __syncthreads();
      int row = tid >> 1, half = tid & 1;
      unsigned char* gp = Cf8 + (long)(rowbase + row) * 1024 + col0 + half * 64;
#pragma unroll
      for (int j = 0; j < 4; ++j)
        *(int4*)(gp + j * 16) = *(const int4*)(SMEM + tid * 64 + j * 16);
    } else {
      // bf16 out: 128x128 x2B = 32KB in LDS
      bf16* Lb = (bf16*)SMEM;
#pragma unroll
      for (int m = 0; m < 2; ++m)
#pragma unroll
        for (int n = 0; n < 2; ++n) {
          int col = wc * 64 + n * 32 + l31;
#pragma unroll
          for (int g = 0; g < 16; ++g) {
            int row = wr * 64 + m * 32 + (g & 3) + 8 * (g >> 2) + 4 * lh;
            Lb[row * 128 + col] = (bf16)acc[m][n][g];
          }
        }
      __syncthreads();
      int row = tid >> 1, half = tid & 1;
      bf16* gp = Cbf + (long)(rowbase + row) * 384 + (col0 - 1024) + half * 64;
#pragma unroll
      for (int j = 0; j < 8; ++j)
        *(int4*)(gp + j * 8) = *(const int4*)(SMEM + tid * 128 + j * 16);
    }
  } else {
    float rs[2][16];
#pragma unroll
    for (int m = 0; m < 2; ++m)
#pragma unroll
      for (int g = 0; g < 16; ++g) rs[m][g] = 0.f;
    int col0 = tile * 128;
#pragma unroll
    for (int n = 0; n < 2; ++n) {
      float bv = bias[col0 + wc * 64 + n * 32 + l31];
#pragma unroll
      for (int m = 0; m < 2; ++m)
#pragma unroll
        for (int g = 0; g < 16; ++g)
          rs[m][g] += __expf(acc[m][n][g] + bv - MREF);
    }
#pragma unroll
    for (int m = 0; m < 2; ++m)
#pragma unroll
      for (int g = 0; g < 16; ++g) {
        float v = rs[m][g];
        v += __shfl_xor(v, 1);
        v += __shfl_xor(v, 2);
        v += __shfl_xor(v, 4);
        v += __shfl_xor(v, 8);
        v += __shfl_xor(v, 16);
        rs[m][g] = v;
      }
    if (l31 == 0) {
      int slotP = tile * 2 + wc;
#pragma unroll
      for (int m = 0; m < 2; ++m)
#pragma unroll
        for (int g = 0; g < 16; ++g) {
          int row = rowbase + wr * 64 + m * 32 + (g & 3) + 8 * (g >> 2) + 4 * lh;
          Ps[(long)row * nslot + slotP] = rs[m][g];
        }
    }
  }
}

// ---------------- bf16 tail body: 128x128 staged + fixed-ref LSE (gathered rows) ----------------

template<int K>
__device__ __forceinline__ void tail_body(
    int wg, const bf16* __restrict__ A, int lda,
    const bf16* __restrict__ B, int nTiles, int tpb,
    const float* __restrict__ bias,
    float* __restrict__ Ps, int nslot,
    const int* __restrict__ rowidx, const int* __restrict__ counts, int cluster,
    bf16* As, bf16* Bs) {
  int split = wg >> 5;
  int rowblk = wg & 31;
  int rowbase = rowblk * 128;
  int nc = counts[cluster];
  if (rowbase >= nc) return;   // block-uniform exit, before any barrier
  int tid = threadIdx.x;
  int w = tid >> 6, llo = tid & 15, lhi = (tid >> 4) & 3;
  int wr = w >> 1, wc = w & 1;

  int srow = tid >> 2;
  int selem = (tid & 3) * 8;
  int sr0 = rowbase + srow, sr1 = sr0 + 64;
  sr0 = rowidx[sr0 < nc ? sr0 : nc - 1];
  sr1 = rowidx[sr1 < nc ? sr1 : nc - 1];
  const bf16* ga0 = A + (long)sr0 * lda + selem;
  const bf16* ga1 = A + (long)sr1 * lda + selem;
  bf16* la0 = As + tid * 8;
  bf16* la1 = As + 2048 + tid * 8;
  bf16* lb0 = Bs + tid * 8;
  bf16* lb1 = Bs + 2048 + tid * 8;

  float rs[4][4];
#pragma unroll
  for (int a = 0; a < 4; ++a)
#pragma unroll
    for (int bq = 0; bq < 4; ++bq) rs[a][bq] = 0.f;

  int t0 = split * tpb;
  int tE = t0 + tpb; if (tE > nTiles) tE = nTiles;

  for (int tile = t0; tile < tE; ++tile) {
    int col0 = tile * 128;
    const bf16* gb0 = B + (long)(col0 + srow) * K + selem;
    const bf16* gb1 = gb0 + (long)64 * K;

    f32x4 acc[4][4];
    f32x4 zero = {0.f, 0.f, 0.f, 0.f};
#pragma unroll
    for (int a = 0; a < 4; ++a)
#pragma unroll
      for (int bq = 0; bq < 4; ++bq) acc[a][bq] = zero;

    for (int k0 = 0; k0 < K; k0 += 32) {
      gl_lds16(ga0 + k0, la0);
      gl_lds16(ga1 + k0, la1);
      gl_lds16(gb0 + k0, lb0);
      gl_lds16(gb1 + k0, lb1);
      __syncthreads();
      bf16x8 af[4], bf_[4];
#pragma unroll
      for (int m = 0; m < 4; ++m)
        af[m] = *(const bf16x8*)(As + (wr * 64 + m * 16 + llo) * 32 + lhi * 8);
#pragma unroll
      for (int n = 0; n < 4; ++n)
        bf_[n] = *(const bf16x8*)(Bs + (wc * 64 + n * 16 + llo) * 32 + lhi * 8);
#pragma unroll
      for (int m = 0; m < 4; ++m)
#pragma unroll
        for (int n = 0; n < 4; ++n)
          acc[m][n] = __builtin_amdgcn_mfma_f32_16x16x32_bf16(af[m], bf_[n], acc[m][n], 0, 0, 0);
      __syncthreads();
    }

    float bv[4];
#pragma unroll
    for (int n = 0; n < 4; ++n) bv[n] = bias[col0 + wc * 64 + n * 16 + llo];
#pragma unroll
    for (int mm = 0; mm < 4; ++mm)
#pragma unroll
      for (int r = 0; r < 4; ++r)
#pragma unroll
        for (int n = 0; n < 4; ++n)
          rs[mm][r] += __expf(acc[mm][n][r] + bv[n] - MREF);
  }

#pragma unroll
  for (int mm = 0; mm < 4; ++mm) {
#pragma unroll
    for (int r = 0; r < 4; ++r) {
      float vv = rs[mm][r];
      vv += __shfl_xor(vv, 1);
      vv += __shfl_xor(vv, 2);
      vv += __shfl_xor(vv, 4);
      vv += __shfl_xor(vv, 8);
      if (llo == 0) {
        int crow = rowbase + wr * 64 + mm * 16 + lhi * 4 + r;
        Ps[(long)crow * nslot + (split * 2 + wc)] = vv;
      }
    }
  }
}

// ---------------- fused tails kernel: 3 independent clusters, one launch ----------------
// segments write disjoint buffers; each keeps its own xcd_swz over 2528.

#define TAIL_NWG 2528

__global__ __launch_bounds__(256, 3) void tails(
    const bf16* __restrict__ projT,
    const bf16* __restrict__ w1p, const float* __restrict__ t1b,
    float* __restrict__ s1P, const int* __restrict__ r1,
    const bf16* __restrict__ w2p, const float* __restrict__ t2b,
    float* __restrict__ s2P, const int* __restrict__ r2,
    const bf16* __restrict__ w3p, const float* __restrict__ t3b,
    float* __restrict__ s3P, const int* __restrict__ r3,
    const int* __restrict__ counts) {
  __shared__ __align__(16) bf16 As[128 * 32];
  __shared__ __align__(16) bf16 Bs[128 * 32];
  int b = blockIdx.x;
  if (b < TAIL_NWG) {
    tail_body<256>(xcd_swz(b, TAIL_NWG), projT, 384, w1p, 79, 1,
                   t1b, s1P, 158, r1, counts, 1, As, Bs);
    return;
  }
  b -= TAIL_NWG;
  if (b < TAIL_NWG) {
    tail_body<64>(xcd_swz(b, TAIL_NWG), projT + 256, 384, w2p, 157, 2,
                  t2b, s2P, 158, r2, counts, 2, As, Bs);
    return;
  }
  b -= TAIL_NWG;
  tail_body<32>(xcd_swz(b, TAIL_NWG), projT + 320, 384, w3p, 79, 1,
                t3b, s3P, 158, r3, counts, 3, As, Bs);
}

// ---------------- merge partials + gathers -> per-token lp (wave per row) ----------------
// SLIM: exactly one fp8 head dot per row (target col for head rows, cluster
// col for tail rows).

__global__ __launch_bounds__(256) void merge_lp(
    const int* __restrict__ target, const int* __restrict__ posmap,
    const unsigned char* __restrict__ projF8, const unsigned char* __restrict__ headw,
    const float* __restrict__ headb, const bf16* __restrict__ projT,
    const bf16* __restrict__ w1p, const float* __restrict__ t1b,
    const bf16* __restrict__ w2p, const float* __restrict__ t2b,
    const bf16* __restrict__ w3p, const float* __restrict__ t3b,
    const float* __restrict__ hs, int NSH,
    const float* __restrict__ s1, int NS1,
    const float* __restrict__ s2, int NS2,
    const float* __restrict__ s3, int NS3,
    float* __restrict__ lp) {
  int lane = threadIdx.x & 63;
  int row = (blockIdx.x * 256 + threadIdx.x) >> 6;
  if (row >= M_TOK) return;

  // head logsumexp from partial slots
  float sh = 0.f;
  for (int sp = lane; sp < NSH; sp += 64) sh += hs[(long)row * NSH + sp];
#pragma unroll
  for (int off = 1; off < 64; off <<= 1) sh += __shfl_xor(sh, off);
  float lseh = MREF + __logf(sh);

  int t = target[row];
  int q = t < 10000 ? 0 : (t < 20000 ? 3 : (t < 40000 ? 2 : 1));
  int col = t < 10000 ? t : 9999 + q;

  // single head dot (fp8 K=1024) at col
  const unsigned char* ap = projF8 + (long)row * 1024 + lane * 16;
  const unsigned char* wp = headw + (long)col * 1024 + lane * 16;
  float d = 0.f;
#pragma unroll
  for (int j = 0; j < 16; ++j) d += fp82f(ap[j]) * fp82f(wp[j]);
#pragma unroll
  for (int off = 1; off < 64; off <<= 1) d += __shfl_xor(d, off);
  float hd = d + headb[col];

  float res;
  if (t < 10000) {
    res = hd - lseh;
  } else {
    const float* sP; const bf16* wP; const float* bP;
    int NS, Kt, offT, base;
    if (t < 20000)      { sP = s1; wP = w1p; bP = t1b; NS = NS1; Kt = 256; offT = 0;   base = 10000; }
    else if (t < 40000) { sP = s2; wP = w2p; bP = t2b; NS = NS2; Kt = 64;  offT = 256; base = 20000; }
    else                { sP = s3; wP = w3p; bP = t3b; NS = NS3; Kt = 32;  offT = 320; base = 40000; }
    int pos = posmap[row];
    float ss = 0.f;
    for (int sp = lane; sp < NS; sp += 64) ss += sP[(long)pos * NS + sp];
#pragma unroll
    for (int off = 1; off < 64; off <<= 1) ss += __shfl_xor(ss, off);
    float lset = MREF + __logf(ss);
    // tail target dot (bf16)
    int wrow = t - base;
    float gt = 0.f;
    for (int k = lane; k < Kt; k += 64)
      gt += (float)projT[(long)row * 384 + offT + k] * (float)wP[(long)wrow * Kt + k];
#pragma unroll
    for (int off = 1; off < 64; off <<= 1) gt += __shfl_xor(gt, off);
    gt += bP[wrow];
    res = (hd - lseh) + (gt - lset);
  }
  if (lane == 0) lp[row] = res;
}

__global__ void neg_mean(const float* __restrict__ lp, float* __restrict__ out) {
  __shared__ float red[256];
  float s = 0.f;
  for (int i = threadIdx.x; i < M_TOK; i += 256) s += lp[i];
  red[threadIdx.x] = s;
  __syncthreads();
  for (int o = 128; o > 0; o >>= 1) {
    if (threadIdx.x < o) red[threadIdx.x] += red[threadIdx.x + o];
    __syncthreads();
  }
  if (threadIdx.x == 0) out[0] = -red[0] / (float)M_TOK;
}

// ---------------- host ----------------

extern "C" void kernel_launch(void* const* d_in, const int* in_sizes, int n_in,
                              void* d_out, int out_size, void* d_ws, size_t ws_size,
                              hipStream_t stream) {
  const float* hidden = (const float*)d_in[0];
  const int*   target = (const int*)d_in[1];
  const float* w0 = (const float*)d_in[2];
  const float* b0 = (const float*)d_in[3];
  const float* p0 = (const float*)d_in[4];
  const float* w1 = (const float*)d_in[5];
  const float* b1 = (const float*)d_in[6];
  const float* p1 = (const float*)d_in[7];
  const float* w2 = (const float*)d_in[8];
  const float* b2 = (const float*)d_in[9];
  const float* p2 = (const float*)d_in[10];
  const float* w3 = (const float*)d_in[11];
  const float* b3 = (const float*)d_in[12];
  const float* p3 = (const float*)d_in[13];
  const float* cw = (const float*)d_in[14];
  const float* cb = (const float*)d_in[15];

  const int NH = 10240;                       // head cols (128-padded)
  const int N1 = 10112, N2 = 20096, N3 = 10112;
  const int TH = NH / 128;                    // 80
  const int NSH = TH * 2, NS1 = 158, NS2 = 158, NS3 = 158;

  char* ws = (char*)d_ws;
  size_t off = 0;
  auto alloc = [&](size_t bytes) -> char* {
    char* p = ws + off;
    off += (bytes + 255) & ~(size_t)255;
    return p;
  };
  unsigned char* hiddenF8 = (unsigned char*)alloc(4096L * 1024);
  unsigned char* pF8      = (unsigned char*)alloc(1408L * 1024);
  unsigned char* headwF8  = (unsigned char*)alloc((long)NH * 1024);
  bf16* w1p   = (bf16*)alloc((long)N1 * 256 * 2);
  bf16* w2p   = (bf16*)alloc((long)N2 * 64 * 2);
  bf16* w3p   = (bf16*)alloc((long)N3 * 32 * 2);
  unsigned char* projF8 = (unsigned char*)alloc(4096L * 1024);
  bf16* projT = (bf16*)alloc(4096L * 384 * 2);
  float* headb = (float*)alloc((long)NH * 4);
  float* t1b   = (float*)alloc((long)N1 * 4);
  float* t2b   = (float*)alloc((long)N2 * 4);
  float* t3b   = (float*)alloc((long)N3 * 4);
  float* hsP = (float*)alloc((size_t)M_TOK * NSH * 4);
  float* s1P = (float*)alloc((size_t)M_TOK * NS1 * 4);
  float* s2P = (float*)alloc((size_t)M_TOK * NS2 * 4);
  float* s3P = (float*)alloc((size_t)M_TOK * NS3 * 4);
  float* lp  = (float*)alloc((size_t)M_TOK * 4);
  int* r1 = (int*)alloc((size_t)M_TOK * 4);
  int* r2 = (int*)alloc((size_t)M_TOK * 4);
  int* r3 = (int*)alloc((size_t)M_TOK * 4);
  int* posmap = (int*)alloc((size_t)M_TOK * 4);
  int* counts = (int*)alloc(16);
  if (ws_size < off) return;  // fail cleanly rather than corrupt

  // 1) fused prep: all conversions, transposes, pads, biases, compaction scan
  const int PREP_BLOCKS = NB0 + NB1 + NB2 + NB3 + NB4 + NB5 + NB6 + 1;
  prep<<<PREP_BLOCKS, 256, 0, stream>>>(
      hidden, w0, cw, w1, w2, w3, p0, p1, p2, p3, b0, cb, b1, b2, b3, target,
      hiddenF8, headwF8, w1p, w2p, w3p, pF8, headb, t1b, t2b, t3b,
      r1, r2, r3, posmap, counts);

  // 2) projection (fp8 MX): proj = hiddenF8 @ pF8^T ; cols<1024 -> fp8, rest -> bf16
  f8gemm<0><<<11 * 32, 256, 0, stream>>>(
      hiddenF8, pF8, projF8, projT, nullptr, nullptr, 0);

  // 3) head logits + fixed-ref LSE partials (fp8 MX, BK=64, counted-vmcnt dbuf)
  f8gemm<1><<<TH * 32, 256, 0, stream>>>(
      projF8, headwF8, nullptr, nullptr, headb, hsP, NSH);

  // 4) fused tails: all three clusters in one launch (disjoint outputs)
  tails<<<3 * TAIL_NWG, 256, 0, stream>>>(
      projT, w1p, t1b, s1P, r1, w2p, t2b, s2P, r2, w3p, t3b, s3P, r3, counts);

  // 5) merge partials + target/cluster gathers -> lp (slim: 1 head dot/row)
  merge_lp<<<1024, 256, 0, stream>>>(
      target, posmap, projF8, headwF8, headb, projT,
      w1p, t1b, w2p, t2b, w3p, t3b,
      hsP, NSH, s1P, NS1, s2P, NS2, s3P, NS3, lp);

  // 6) reduce
  neg_mean<<<1, 256, 0, stream>>>(lp, (float*)d_out);
}